// Round 15
// baseline (6664.044 us; speedup 1.0000x reference)
//
#include <hip/hip_runtime.h>
#include <hip/hip_bf16.h>
#include <stdint.h>

typedef unsigned int uint;
typedef unsigned short ushort;
typedef unsigned long long u64;
typedef __attribute__((ext_vector_type(8))) short s8v;
typedef __attribute__((ext_vector_type(4))) float f4v;

#define T_STEPS 128
#define BQ 16
#define HID 512
#define NSLOT 1024
#define MD 64
#define VOCAB 32000
#define BETA 1.000001f
#define EPSN 1e-8f

#define NWK 128          // worker WGs (proj+slot+gp roles)
#define NBT 16           // batch WGs (merge+rv+gates+LSTM)
#define NGEMM 256        // fused gemm blocks
#define GM_NT 250

// flag lines (128B apart), monotonic generations, memset-0 per launch
#define LF_FH(b)  ((b)*32)            // h(t) ready (gen t+1); batch -> workers+gemm
#define LF_FP(w)  ((16+(w))*32)       // proj WG w keys+ew for t (gen t+1)
#define LF_FC(w)  ((48+(w))*32)       // slot WG w cand for t (gen t+1)
#define LF_FW(b)  ((176+(b))*32)      // batch b wlist(t) visible (gen t+1)
#define LF_FG(w)  ((192+(w))*32)      // gp(t) from worker w (gen t+1)
#define NLINES    320

// agent-coherent (bypass L1/L2); batched waitcnt (+sched_barrier, rule #18)
#define AL4(dst, p) asm volatile("global_load_dwordx4 %0, %1, off sc0 sc1" : "=v"(dst) : "v"(p))
#define ALF(dst, p) asm volatile("global_load_dword %0, %1, off sc0 sc1" : "=v"(dst) : "v"(p))
#define AWAIT() do { asm volatile("s_waitcnt vmcnt(0)" ::: "memory"); __builtin_amdgcn_sched_barrier(0); } while(0)
#define DRAIN() asm volatile("s_waitcnt vmcnt(0)" ::: "memory")

__device__ __forceinline__ float sigm(float x){ return 1.f/(1.f+expf(-x)); }
__device__ __forceinline__ void astoref(float* p, float v){
  __hip_atomic_store(p, v, __ATOMIC_RELAXED, __HIP_MEMORY_SCOPE_AGENT);
}
__device__ __forceinline__ void astoreu32(uint* p, uint v){
  __hip_atomic_store(p, v, __ATOMIC_RELAXED, __HIP_MEMORY_SCOPE_AGENT);
}
__device__ __forceinline__ void astoreu64(u64* p, u64 v){
  __hip_atomic_store(p, v, __ATOMIC_RELAXED, __HIP_MEMORY_SCOPE_AGENT);
}
__device__ __forceinline__ u64 aloadu64(const u64* p){
  return __hip_atomic_load((u64*)p, __ATOMIC_RELAXED, __HIP_MEMORY_SCOPE_AGENT);
}
__device__ __forceinline__ uint aloadu32(const uint* p){
  return __hip_atomic_load((uint*)p, __ATOMIC_RELAXED, __HIP_MEMORY_SCOPE_AGENT);
}
__device__ __forceinline__ void poll1(const uint* p, uint gen){
  while (aloadu32(p) < gen) __builtin_amdgcn_s_sleep(2);
}
__device__ __forceinline__ void poll64(const uint* p, uint gen){
  while (aloadu32(p) < gen) __builtin_amdgcn_s_sleep(64);
}

// pack (score, slot): u64 max == (max value, min slot on ties) — matches lax.top_k
__device__ __forceinline__ u64 packsc(float v, int slot){
  uint u = __float_as_uint(v);
  u = (u & 0x80000000u) ? ~u : (u | 0x80000000u);
  return ((u64)u << 10) | (u64)(1023 - slot);
}
__device__ __forceinline__ float unpackval(u64 p){
  uint u = (uint)(p >> 10);
  uint bits = (u & 0x80000000u) ? (u & 0x7fffffffu) : ~u;
  return __uint_as_float(bits);
}
__device__ __forceinline__ int unpackslot(u64 p){ return 1023 - (int)(p & 1023u); }

// bf16 split helpers
__device__ __forceinline__ ushort f2bf(float x){
  __hip_bfloat16 h = __float2bfloat16(x);
  return *(ushort*)&h;
}
__device__ __forceinline__ float bf2f(ushort u){
  __hip_bfloat16 h; *(ushort*)&h = u;
  return __bfloat162float(h);
}

// LDS float offsets (worker); batch uses low region; gemm overlays as ushort
#define L_MEM  0
#define L_NRM  8704
#define L_HS   8832
#define L_KEY  17088
#define L_KNRM 17600
#define L_SC   17608
#define L_WV   18632
#define L_ER   18888
#define L_WL   19144
#define L_TOT  19208

// ---------------- pre-kernels ----------------
__global__ __launch_bounds__(256) void prep_emb(const float* __restrict__ E,
                                                const int* __restrict__ seq,
                                                float* __restrict__ EMB){
  int m = blockIdx.x, t = m >> 4, b = m & 15;
  int x = seq[b*T_STEPS + t];
  EMB[(size_t)m*256 + threadIdx.x] = E[(size_t)x*256 + threadIdx.x];
}

// G_emb[m][p] packed p=u*4+g, r=g*512+u
__global__ __launch_bounds__(256) void gemm_emb(const float* __restrict__ A,
                                                const float* __restrict__ W_ih,
                                                const float* __restrict__ b_ih,
                                                const float* __restrict__ b_hh,
                                                float* __restrict__ C){
  __shared__ __align__(16) float As[16*68];
  __shared__ __align__(16) float Bs[16*68];
  int mt = blockIdx.x & 31, nt = blockIdx.x >> 5;
  int m0 = mt*64, n0 = nt*64;
  int tx = threadIdx.x & 15, ty = threadIdx.x >> 4;
  float acc[4][4] = {};
  for (int k0 = 0; k0 < 256; k0 += 16){
    int mm = threadIdx.x >> 2, kq = (threadIdx.x & 3)*4;
    float4 a = *(const float4*)(A + (size_t)(m0+mm)*256 + k0 + kq);
    As[(kq+0)*68+mm]=a.x; As[(kq+1)*68+mm]=a.y; As[(kq+2)*68+mm]=a.z; As[(kq+3)*68+mm]=a.w;
    int pp = n0 + mm;
    int r = (pp & 3)*512 + (pp >> 2);
    float4 bv = *(const float4*)(W_ih + (size_t)r*320 + k0 + kq);
    Bs[(kq+0)*68+mm]=bv.x; Bs[(kq+1)*68+mm]=bv.y; Bs[(kq+2)*68+mm]=bv.z; Bs[(kq+3)*68+mm]=bv.w;
    __syncthreads();
    #pragma unroll
    for (int kk = 0; kk < 16; ++kk){
      float4 av = *(const float4*)(As + kk*68 + ty*4);
      float4 bb = *(const float4*)(Bs + kk*68 + tx*4);
      float aa[4] = {av.x,av.y,av.z,av.w};
      float bv2[4] = {bb.x,bb.y,bb.z,bb.w};
      #pragma unroll
      for (int i = 0; i < 4; ++i)
        #pragma unroll
        for (int j = 0; j < 4; ++j)
          acc[i][j] = fmaf(aa[i], bv2[j], acc[i][j]);
    }
    __syncthreads();
  }
  #pragma unroll
  for (int i = 0; i < 4; ++i){
    int m = m0 + ty*4 + i;
    #pragma unroll
    for (int j = 0; j < 4; ++j){
      int pp = n0 + tx*4 + j;
      int r = (pp & 3)*512 + (pp >> 2);
      C[(size_t)m*2048 + pp] = acc[i][j] + b_ih[r] + b_hh[r];
    }
  }
}

// WT[k][p] = W_ih[r(p)][256+k]  (packed-p rv-weight transpose)
__global__ __launch_bounds__(256) void make_wrvT(const float* __restrict__ W_ih,
                                                 float* __restrict__ WT){
  int idx = blockIdx.x*256 + threadIdx.x;
  int k = idx >> 11, p = idx & 2047;
  int r = (p & 3)*512 + (p >> 2);
  WT[idx] = W_ih[(size_t)r*320 + 256 + k];
}

// ---- split W_out (512x32000 fp32) -> BThi/BTlo [32000][512] bf16 (transposed) ----
__global__ __launch_bounds__(256) void split_BT(const float* __restrict__ W,
                                                ushort* __restrict__ BThi,
                                                ushort* __restrict__ BTlo){
  __shared__ float tl[32][33];
  int kt = blockIdx.x & 15, nt = blockIdx.x >> 4;
  int k0 = kt*32, n0 = nt*32;
  int tx = threadIdx.x & 31, ty = threadIdx.x >> 5;
  #pragma unroll
  for (int i = 0; i < 4; ++i)
    tl[ty + i*8][tx] = W[(size_t)(k0 + ty + i*8)*VOCAB + n0 + tx];
  __syncthreads();
  #pragma unroll
  for (int i = 0; i < 4; ++i){
    float x = tl[tx][ty + i*8];
    ushort hi = f2bf(x);
    ushort lo = f2bf(x - bf2f(hi));
    size_t o = (size_t)(n0 + ty + i*8)*512 + k0 + tx;
    BThi[o] = hi; BTlo[o] = lo;
  }
}

// ---------------- R15: R14 recurrence + fused overlapped MFMA logits GEMM ----------------
// blocks [0,128): workers; [128,144): batch WGs; [144,400): gemm tiles (poll H progress)
__global__ __launch_bounds__(256) void recur_kernel(
    const float* __restrict__ W_hh, const float* __restrict__ WT,
    const float* __restrict__ W_rk, const float* __restrict__ b_rk,
    const float* __restrict__ W_wk, const float* __restrict__ b_wk,
    const float* __restrict__ W_wv, const float* __restrict__ b_wv,
    const float* __restrict__ W_er, const float* __restrict__ b_er,
    const float* __restrict__ G_emb, float* __restrict__ H_all,
    float* __restrict__ H_pub, float* __restrict__ mem_g,
    float* __restrict__ projpub, float* __restrict__ gatespub,
    u64* __restrict__ cand, u64* __restrict__ wlist,
    const ushort* __restrict__ BThi, const ushort* __restrict__ BTlo,
    const float* __restrict__ b_out, float* __restrict__ C_out,
    uint* __restrict__ arrv)
{
  __shared__ __align__(16) float smem[L_TOT];
  const int tid = threadIdx.x;
  const int wg  = blockIdx.x;

  if (wg < NWK){
    // =================== WORKER (R14 verbatim) ===================
    float* mem_s  = smem + L_MEM;
    float* nrm_s  = smem + L_NRM;
    float* hs     = smem + L_HS;
    float* key_s  = smem + L_KEY;
    float* knrm_s = smem + L_KNRM;
    float* sc_s   = smem + L_SC;
    float* wv_s   = smem + L_WV;
    float* er_s   = smem + L_ER;
    u64*   wl_s   = (u64*)(smem + L_WL);

    const int b_s = wg >> 3, rg = wg & 7, s0 = rg*128;
    const int gb = tid >> 4, gc = tid & 15;
    const int pcol = wg*16 + gc;
    const int rrow = (pcol & 3)*512 + (pcol >> 2);
    float* mslice_g = mem_g + ((size_t)b_s*NSLOT + s0)*MD;
    const float* W1 = (wg < 16) ? W_rk : W_wk;
    const float* B1 = (wg < 16) ? b_rk : b_wk;
    const float* W2 = (wg < 16) ? W_wv : W_er;
    const float* B2 = (wg < 16) ? b_wv : b_er;
    const int cc = (wg & 15)*16 + gc;
    const float pb1 = (wg < 32) ? B1[cc] : 0.f;
    const float pb2 = (wg < 32) ? B2[cc] : 0.f;

    for (int i = tid; i < 128*MD; i += 256){
      mem_s[(i >> 6)*68 + (i & 63)] = 1e-6f;
      astoref(mslice_g + i, 1e-6f);
    }
    __syncthreads();
    {
      int s = tid >> 1, half = tid & 1;
      const float4* mp = (const float4*)(mem_s + s*68 + half*32);
      float sum = 0.f;
      #pragma unroll
      for (int q = 0; q < 8; ++q){
        float4 v = mp[q];
        sum = fmaf(v.x,v.x,sum); sum = fmaf(v.y,v.y,sum);
        sum = fmaf(v.z,v.z,sum); sum = fmaf(v.w,v.w,sum);
      }
      sum += __shfl_xor(sum, 1);
      if (half == 0) nrm_s[s] = sqrtf(sum) + EPSN;
    }
    __syncthreads();

    #pragma clang loop unroll(disable)
    for (int t = 0; t < T_STEPS-1; ++t){
      const int par = t & 1, parp = par ^ 1;
      if (t > 0){
        if (tid == 0) poll1(arrv + LF_FW(b_s), (uint)t);
        __syncthreads();
        if (tid < 32) wl_s[tid] = aloadu64(wlist + (size_t)b_s*32 + tid);
        if (tid < 64){
          float4 v; AL4(v, (const float4*)(projpub + (size_t)parp*BQ*1024 + (size_t)b_s*1024 + 512) + tid);
          AWAIT();
          *(float4*)(wv_s + tid*4) = v;
        } else if (tid < 128){
          int i = tid - 64;
          float4 v; AL4(v, (const float4*)(projpub + (size_t)parp*BQ*1024 + (size_t)b_s*1024 + 768) + i);
          AWAIT();
          *(float4*)(er_s + i*4) = v;
        }
        __syncthreads();
        if (tid < 64){
          const int d = tid;
          #pragma unroll 1
          for (int e = 0; e < 32; ++e){
            u64 w64 = wl_s[e];
            int sl = (int)(w64 & 0xffffffffu);
            if (sl >= s0 && sl < s0+128){
              float w = __uint_as_float((uint)(w64 >> 32));
              mem_s[(sl-s0)*68 + d] *= (1.f - w*er_s[(e >> 3)*64 + d]);
            }
          }
          #pragma unroll 1
          for (int e = 0; e < 32; ++e){
            u64 w64 = wl_s[e];
            int sl = (int)(w64 & 0xffffffffu);
            if (sl >= s0 && sl < s0+128){
              float w = __uint_as_float((uint)(w64 >> 32));
              mem_s[(sl-s0)*68 + d] += w*wv_s[(e >> 3)*64 + d];
            }
          }
          #pragma unroll 1
          for (int e = 0; e < 32; ++e){
            u64 w64 = wl_s[e];
            int sl = (int)(w64 & 0xffffffffu);
            if (sl >= s0 && sl < s0+128)
              astoref(mslice_g + (sl-s0)*MD + d, mem_s[(sl-s0)*68 + d]);
          }
        }
        __syncthreads();
        {
          int s = tid >> 1, half = tid & 1;
          const float4* mp = (const float4*)(mem_s + s*68 + half*32);
          float sum = 0.f;
          #pragma unroll
          for (int q = 0; q < 8; ++q){
            float4 v = mp[q];
            sum = fmaf(v.x,v.x,sum); sum = fmaf(v.y,v.y,sum);
            sum = fmaf(v.z,v.z,sum); sum = fmaf(v.w,v.w,sum);
          }
          sum += __shfl_xor(sum, 1);
          if (half == 0) nrm_s[s] = sqrtf(sum) + EPSN;
        }
      }
      if (tid < 16) poll1(arrv + LF_FH(tid), (uint)(t+1));
      __syncthreads();
      {
        float4 v0,v1,v2,v3,v4,v5,v6,v7;
        const float4* hp = (const float4*)H_pub;
        AL4(v0, hp + tid);        AL4(v1, hp + tid + 256);
        AL4(v2, hp + tid + 512);  AL4(v3, hp + tid + 768);
        AL4(v4, hp + tid + 1024); AL4(v5, hp + tid + 1280);
        AL4(v6, hp + tid + 1536); AL4(v7, hp + tid + 1792);
        AWAIT();
        int i;
        i = tid;        *(float4*)(hs + (i>>7)*516 + (i&127)*4) = v0;
        i = tid + 256;  *(float4*)(hs + (i>>7)*516 + (i&127)*4) = v1;
        i = tid + 512;  *(float4*)(hs + (i>>7)*516 + (i&127)*4) = v2;
        i = tid + 768;  *(float4*)(hs + (i>>7)*516 + (i&127)*4) = v3;
        i = tid + 1024; *(float4*)(hs + (i>>7)*516 + (i&127)*4) = v4;
        i = tid + 1280; *(float4*)(hs + (i>>7)*516 + (i&127)*4) = v5;
        i = tid + 1536; *(float4*)(hs + (i>>7)*516 + (i&127)*4) = v6;
        i = tid + 1792; *(float4*)(hs + (i>>7)*516 + (i&127)*4) = v7;
      }
      __syncthreads();
      if (wg < 32){
        float a0=0.f,a1=0.f,b0=0.f,b1=0.f;
        const float* hp = hs + gb*516;
        const float* w1 = W1 + cc;
        const float* w2 = W2 + cc;
        #pragma unroll 4
        for (int k = 0; k < 512; k += 2){
          float h0 = hp[k], h1 = hp[k+1];
          a0 = fmaf(h0, w1[(size_t)k*256], a0);
          b0 = fmaf(h0, w2[(size_t)k*256], b0);
          a1 = fmaf(h1, w1[(size_t)(k+1)*256], a1);
          b1 = fmaf(h1, w2[(size_t)(k+1)*256], b1);
        }
        float v1 = a0 + a1 + pb1;
        float v2 = b0 + b1 + pb2;
        if (wg >= 16) v2 = sigm(v2);
        astoref(projpub + (size_t)par*BQ*1024 + (size_t)gb*1024 + wg*16 + gc, v1);
        astoref(projpub + (size_t)par*BQ*1024 + (size_t)gb*1024 + 512 + wg*16 + gc, v2);
      }
      DRAIN();
      __syncthreads();
      if (wg < 32 && tid == 0) astoreu32(arrv + LF_FP(wg), (uint)(t+1));
      if (tid < 32) poll1(arrv + LF_FP(tid), (uint)(t+1));
      __syncthreads();
      if (tid < 128){
        float4 kv; AL4(kv, (const float4*)(projpub + (size_t)par*BQ*1024 + (size_t)b_s*1024) + tid);
        AWAIT();
        *(float4*)(key_s + tid*4) = kv;
      }
      __syncthreads();
      if (tid < 8){
        const float4* kp = (const float4*)(key_s + tid*MD);
        float sum = 0.f;
        #pragma unroll
        for (int q = 0; q < 16; ++q){
          float4 v = kp[q];
          sum = fmaf(v.x,v.x,sum); sum = fmaf(v.y,v.y,sum);
          sum = fmaf(v.z,v.z,sum); sum = fmaf(v.w,v.w,sum);
        }
        knrm_s[tid] = sqrtf(sum) + EPSN;
      }
      __syncthreads();
      {
        int s = tid >> 1, kh = tid & 1;
        const float4* mp = (const float4*)(mem_s + s*68);
        float rnm = 1.f / nrm_s[s];
        float acc4[4] = {0.f,0.f,0.f,0.f};
        #pragma unroll
        for (int q = 0; q < 16; ++q){
          float4 m = mp[q];
          #pragma unroll
          for (int kk = 0; kk < 4; ++kk){
            float4 k4 = *(const float4*)(key_s + (kh*4+kk)*MD + q*4);
            acc4[kk] = fmaf(m.x,k4.x,acc4[kk]); acc4[kk] = fmaf(m.y,k4.y,acc4[kk]);
            acc4[kk] = fmaf(m.z,k4.z,acc4[kk]); acc4[kk] = fmaf(m.w,k4.w,acc4[kk]);
          }
        }
        #pragma unroll
        for (int kk = 0; kk < 4; ++kk){
          int key = kh*4 + kk;
          sc_s[key*128 + s] = BETA * acc4[kk] * rnm / knrm_s[key];
        }
      }
      __syncthreads();
      {
        int wid = tid >> 6, lane = tid & 63;
        #pragma unroll
        for (int kk = 0; kk < 2; ++kk){
          int key = wid*2 + kk;
          u64 p0 = packsc(sc_s[key*128 + lane],      s0 + lane);
          u64 p1 = packsc(sc_s[key*128 + 64 + lane], s0 + 64 + lane);
          #pragma unroll
          for (int r = 0; r < 8; ++r){
            u64 m = p0 > p1 ? p0 : p1;
            #pragma unroll
            for (int o = 32; o; o >>= 1){ u64 q = __shfl_xor(m, o); if (q > m) m = q; }
            if (p0 == m) p0 = 0; else if (p1 == m) p1 = 0;
            if (lane == 0) astoreu64(cand + (((size_t)b_s*8 + key)*8 + rg)*8 + r, m);
          }
        }
      }
      DRAIN();
      __syncthreads();
      if (tid == 0) astoreu32(arrv + LF_FC(wg), (uint)(t+1));
      {
        float a0 = G_emb[(size_t)((t+1)*BQ + gb)*2048 + pcol];
        float a1 = 0.f, a2 = 0.f, a3 = 0.f;
        const float4* wh = (const float4*)(W_hh + (size_t)rrow*HID);
        const float4* xv = (const float4*)(hs + gb*516);
        #pragma unroll 2
        for (int k = 0; k < 128; k += 4){
          float4 w, x;
          w=wh[k+0]; x=xv[k+0]; a0=fmaf(w.x,x.x,a0); a0=fmaf(w.y,x.y,a0); a0=fmaf(w.z,x.z,a0); a0=fmaf(w.w,x.w,a0);
          w=wh[k+1]; x=xv[k+1]; a1=fmaf(w.x,x.x,a1); a1=fmaf(w.y,x.y,a1); a1=fmaf(w.z,x.z,a1); a1=fmaf(w.w,x.w,a1);
          w=wh[k+2]; x=xv[k+2]; a2=fmaf(w.x,x.x,a2); a2=fmaf(w.y,x.y,a2); a2=fmaf(w.z,x.z,a2); a2=fmaf(w.w,x.w,a2);
          w=wh[k+3]; x=xv[k+3]; a3=fmaf(w.x,x.x,a3); a3=fmaf(w.y,x.y,a3); a3=fmaf(w.z,x.z,a3); a3=fmaf(w.w,x.w,a3);
        }
        astoref(gatespub + (size_t)gb*2048 + pcol, (a0+a1)+(a2+a3));
      }
      DRAIN();
      __syncthreads();
      if (tid == 0) astoreu32(arrv + LF_FG(wg), (uint)(t+1));
    }
  } else if (wg < NWK + NBT){
    // =================== BATCH WG (R14 + astoref H_all) ===================
    const int b = wg - NWK;
    float* rv_st = smem;            // [4][64]
    float* rv_s  = smem + 256;      // [64]
    float* gl    = smem + 320;      // [2048]
    float c0, c1;
    {
      float4 gA = *(const float4*)(G_emb + (size_t)b*2048 + tid*8);
      float4 gB = *(const float4*)(G_emb + (size_t)b*2048 + tid*8 + 4);
      c0 = sigm(gA.x)*tanhf(gA.z);
      float h0v = sigm(gA.w)*tanhf(c0);
      c1 = sigm(gB.x)*tanhf(gB.z);
      float h1v = sigm(gB.w)*tanhf(c1);
      astoref(H_pub + (size_t)b*HID + tid*2,     h0v);
      astoref(H_pub + (size_t)b*HID + tid*2 + 1, h1v);
      astoref(H_all + (size_t)b*HID + tid*2,     h0v);
      astoref(H_all + (size_t)b*HID + tid*2 + 1, h1v);
    }
    DRAIN();
    __syncthreads();
    if (tid == 0) astoreu32(arrv + LF_FH(b), 1u);

    #pragma clang loop unroll(disable)
    for (int t = 0; t < T_STEPS-1; ++t){
      if (tid < 8) poll1(arrv + LF_FC(b*8 + tid), (uint)(t+1));
      __syncthreads();
      {
        int wid = tid >> 6, lane = tid & 63;
        #pragma unroll
        for (int kk = 0; kk < 2; ++kk){
          int key = wid*2 + kk;
          u64 pv = aloadu64(cand + (((size_t)b*8 + key)*8 + (lane >> 3))*8 + (lane & 7));
          u64 sel = 0;
          #pragma unroll
          for (int r = 0; r < 8; ++r){
            u64 m = pv;
            #pragma unroll
            for (int o = 32; o; o >>= 1){ u64 q = __shfl_xor(m, o); if (q > m) m = q; }
            if (pv == m) pv = 0;
            if (lane == r) sel = m;
          }
          float val = unpackval(sel);
          int slot = unpackslot(sel);
          float vmax = __shfl(val, 0);
          float e = (lane < 8) ? expf(val - vmax) : 0.f;
          float ssum = e;
          #pragma unroll
          for (int o = 32; o; o >>= 1) ssum += __shfl_xor(ssum, o);
          float w = e / ssum;
          if (key < 4){
            int sls[8];
            #pragma unroll
            for (int i = 0; i < 8; ++i) sls[i] = __shfl(slot, i);
            float mv[8];
            #pragma unroll
            for (int i = 0; i < 8; ++i)
              ALF(mv[i], mem_g + ((size_t)b*NSLOT + sls[i])*MD + lane);
            AWAIT();
            float acc = 0.f;
            #pragma unroll
            for (int i = 0; i < 8; ++i) acc = fmaf(__shfl(w, i), mv[i], acc);
            rv_st[key*64 + lane] = acc;
          } else if (lane < 8){
            astoreu64(wlist + (size_t)b*32 + (key-4)*8 + lane,
                      ((u64)__float_as_uint(w) << 32) | (u64)(uint)slot);
          }
        }
      }
      DRAIN();
      __syncthreads();
      if (tid < 64)
        rv_s[tid] = 0.25f*(rv_st[tid] + rv_st[64+tid] + rv_st[128+tid] + rv_st[192+tid]);
      if (tid == 0) astoreu32(arrv + LF_FW(b), (uint)(t+1));
      if (tid < 128) poll1(arrv + LF_FG(tid), (uint)(t+1));
      __syncthreads();
      {
        float g8[8];
        #pragma unroll
        for (int q = 0; q < 8; ++q)
          ALF(g8[q], gatespub + (size_t)b*2048 + tid + 256*q);
        AWAIT();
        #pragma unroll 2
        for (int d = 0; d < 64; ++d){
          float r = rv_s[d];
          const float* wrow = WT + (size_t)d*2048 + tid;
          #pragma unroll
          for (int q = 0; q < 8; ++q)
            g8[q] = fmaf(r, wrow[256*q], g8[q]);
        }
        #pragma unroll
        for (int q = 0; q < 8; ++q) gl[tid + 256*q] = g8[q];
      }
      __syncthreads();
      {
        float gi0 = gl[tid*8+0], gf0 = gl[tid*8+1], gg0 = gl[tid*8+2], go0 = gl[tid*8+3];
        float gi1 = gl[tid*8+4], gf1 = gl[tid*8+5], gg1 = gl[tid*8+6], go1 = gl[tid*8+7];
        c0 = sigm(gf0)*c0 + sigm(gi0)*tanhf(gg0);
        float h0v = sigm(go0)*tanhf(c0);
        c1 = sigm(gf1)*c1 + sigm(gi1)*tanhf(gg1);
        float h1v = sigm(go1)*tanhf(c1);
        astoref(H_pub + (size_t)b*HID + tid*2,     h0v);
        astoref(H_pub + (size_t)b*HID + tid*2 + 1, h1v);
        astoref(H_all + (size_t)((t+1)*BQ + b)*HID + tid*2,     h0v);
        astoref(H_all + (size_t)((t+1)*BQ + b)*HID + tid*2 + 1, h1v);
      }
      DRAIN();
      __syncthreads();
      if (tid == 0) astoreu32(arrv + LF_FH(b), (uint)(t+2));
    }
  } else {
    // =================== GEMM role: overlapped MFMA logits tiles ===================
    const int g = wg - (NWK + NBT);
    ushort* ldsu = (ushort*)smem;                 // 4*128*40 ushorts = 40 KB
    const int wv_ = tid >> 6, lane = tid & 63;
    const int wm = (wv_ & 1)*64, wn = (wv_ >> 1)*64;
    const int fr = lane & 15, kh = (lane >> 4)*8;
    const int ar = tid >> 1, ahalf = tid & 1;     // A staging: row, 16-col half
    const int sr = tid & 127, selb = tid >> 7;    // B staging: row, hi/lo

    for (int tile = g; tile < 16*GM_NT; tile += NGEMM){
      int mt = tile / GM_NT, nt = tile - mt*GM_NT;
      int m0 = mt*128, n0 = nt*128;
      uint need = (uint)(mt*8 + 8);               // h rows through t=mt*8+7
      if (tid < 16) poll64(arrv + LF_FH(tid), need);
      __syncthreads();
      f4v acc[4][4];
      #pragma unroll
      for (int i = 0; i < 4; ++i)
        #pragma unroll
        for (int j = 0; j < 4; ++j)
          acc[i][j] = (f4v){0.f,0.f,0.f,0.f};
      const float* srcA = H_all + (size_t)(m0 + ar)*512 + ahalf*16;
      const ushort* srcB = (selb ? BTlo : BThi) + (size_t)(n0 + sr)*512;
      ushort* dstAh = ldsu + 0*5120 + ar*40 + ahalf*16;
      ushort* dstAl = ldsu + 1*5120 + ar*40 + ahalf*16;
      ushort* dstB  = ldsu + (size_t)(2+selb)*5120 + sr*40;
      for (int ks = 0; ks < 16; ++ks){
        const int k0 = ks*32;
        __syncthreads();
        float4 fa0, fa1, fa2, fa3;
        AL4(fa0, (const float4*)(srcA + k0));       // uncached: avoids stale-L2 risk
        AL4(fa1, (const float4*)(srcA + k0 + 4));
        AL4(fa2, (const float4*)(srcA + k0 + 8));
        AL4(fa3, (const float4*)(srcA + k0 + 12));
        uint4 b0 = *(const uint4*)(srcB + k0);      // BT pre-split before launch: cached OK
        uint4 b1 = *(const uint4*)(srcB + k0 + 8);
        uint4 b2 = *(const uint4*)(srcB + k0 + 16);
        uint4 b3 = *(const uint4*)(srcB + k0 + 24);
        AWAIT();
        float fa[16] = {fa0.x,fa0.y,fa0.z,fa0.w, fa1.x,fa1.y,fa1.z,fa1.w,
                        fa2.x,fa2.y,fa2.z,fa2.w, fa3.x,fa3.y,fa3.z,fa3.w};
        #pragma unroll
        for (int j = 0; j < 16; ++j){
          ushort hi = f2bf(fa[j]);
          dstAh[j] = hi;
          dstAl[j] = f2bf(fa[j] - bf2f(hi));
        }
        *(uint4*)(dstB +  0) = b0; *(uint4*)(dstB +  8) = b1;
        *(uint4*)(dstB + 16) = b2; *(uint4*)(dstB + 24) = b3;
        __syncthreads();
        s8v ah[4], al[4], bh[4], bl[4];
        #pragma unroll
        for (int mi = 0; mi < 4; ++mi){
          ah[mi] = *(const s8v*)(ldsu + 0*5120 + (wm + mi*16 + fr)*40 + kh);
          al[mi] = *(const s8v*)(ldsu + 1*5120 + (wm + mi*16 + fr)*40 + kh);
        }
        #pragma unroll
        for (int ni = 0; ni < 4; ++ni){
          bh[ni] = *(const s8v*)(ldsu + 2*5120 + (wn + ni*16 + fr)*40 + kh);
          bl[ni] = *(const s8v*)(ldsu + 3*5120 + (wn + ni*16 + fr)*40 + kh);
        }
        #pragma unroll
        for (int mi = 0; mi < 4; ++mi)
          #pragma unroll
          for (int ni = 0; ni < 4; ++ni){
            acc[mi][ni] = __builtin_amdgcn_mfma_f32_16x16x32_bf16(ah[mi], bh[ni], acc[mi][ni], 0, 0, 0);
            acc[mi][ni] = __builtin_amdgcn_mfma_f32_16x16x32_bf16(ah[mi], bl[ni], acc[mi][ni], 0, 0, 0);
            acc[mi][ni] = __builtin_amdgcn_mfma_f32_16x16x32_bf16(al[mi], bh[ni], acc[mi][ni], 0, 0, 0);
            acc[mi][ni] = __builtin_amdgcn_mfma_f32_16x16x32_bf16(al[mi], bl[ni], acc[mi][ni], 0, 0, 0);
          }
      }
      // epilogue: C/D layout col=lane&15, row=(lane>>4)*4+j  [m89-verified]
      #pragma unroll
      for (int ni = 0; ni < 4; ++ni){
        int col = n0 + wn + ni*16 + fr;
        float bz = b_out[col];
        #pragma unroll
        for (int mi = 0; mi < 4; ++mi){
          #pragma unroll
          for (int j = 0; j < 4; ++j){
            int row = m0 + wm + mi*16 + (lane >> 4)*4 + j;   // row = t*16 + b
            C_out[((size_t)(row & 15)*T_STEPS + (row >> 4))*VOCAB + col] = acc[mi][ni][j] + bz;
          }
        }
      }
      __syncthreads();
    }
  }
}

// ---------------- fp32 fallback GEMM (only if ws too small for BT splits) ----------------
__global__ __launch_bounds__(256) void gemm_out(const float* __restrict__ A,
                                                const float* __restrict__ Bmat,
                                                const float* __restrict__ bias,
                                                float* __restrict__ C){
  __shared__ __align__(16) float As[16*132];
  __shared__ __align__(16) float Bs[16*64];
  int mt = blockIdx.x & 15, nt = blockIdx.x >> 4;
  int m0 = mt*128, n0 = nt*64;
  int tx = threadIdx.x & 15, ty = threadIdx.x >> 4;
  float acc[8][4] = {};
  for (int k0 = 0; k0 < 512; k0 += 16){
    int mm = threadIdx.x >> 1, kq = (threadIdx.x & 1)*8;
    float4 a0 = *(const float4*)(A + (size_t)(m0+mm)*512 + k0 + kq);
    float4 a1 = *(const float4*)(A + (size_t)(m0+mm)*512 + k0 + kq + 4);
    As[(kq+0)*132+mm]=a0.x; As[(kq+1)*132+mm]=a0.y; As[(kq+2)*132+mm]=a0.z; As[(kq+3)*132+mm]=a0.w;
    As[(kq+4)*132+mm]=a1.x; As[(kq+5)*132+mm]=a1.y; As[(kq+6)*132+mm]=a1.z; As[(kq+7)*132+mm]=a1.w;
    int kk2 = threadIdx.x >> 4, nq = (threadIdx.x & 15)*4;
    *(float4*)(Bs + kk2*64 + nq) = *(const float4*)(Bmat + (size_t)(k0+kk2)*VOCAB + n0 + nq);
    __syncthreads();
    #pragma unroll
    for (int kk = 0; kk < 16; ++kk){
      float4 x0 = *(const float4*)(As + kk*132 + ty*8);
      float4 x1 = *(const float4*)(As + kk*132 + ty*8 + 4);
      float4 bv = *(const float4*)(Bs + kk*64 + tx*4);
      float aa[8] = {x0.x,x0.y,x0.z,x0.w,x1.x,x1.y,x1.z,x1.w};
      float bb[4] = {bv.x,bv.y,bv.z,bv.w};
      #pragma unroll
      for (int i = 0; i < 8; ++i)
        #pragma unroll
        for (int j = 0; j < 4; ++j)
          acc[i][j] = fmaf(aa[i], bb[j], acc[i][j]);
    }
    __syncthreads();
  }
  #pragma unroll
  for (int i = 0; i < 8; ++i){
    int m = m0 + ty*8 + i;
    int bq = m & 15, tt = m >> 4;
    float* crow = C + ((size_t)bq*T_STEPS + tt)*VOCAB + n0 + tx*4;
    #pragma unroll
    for (int j = 0; j < 4; ++j) crow[j] = acc[i][j] + bias[n0 + tx*4 + j];
  }
}

extern "C" void kernel_launch(void* const* d_in, const int* in_sizes, int n_in,
                              void* d_out, int out_size, void* d_ws, size_t ws_size,
                              hipStream_t stream){
  const int*   seq   = (const int*)d_in[0];
  const float* E     = (const float*)d_in[1];
  const float* W_ih  = (const float*)d_in[2];
  const float* W_hh  = (const float*)d_in[3];
  const float* b_ih  = (const float*)d_in[4];
  const float* b_hh  = (const float*)d_in[5];
  const float* W_out = (const float*)d_in[6];
  const float* b_out = (const float*)d_in[7];
  const float* W_rk  = (const float*)d_in[8];
  const float* b_rk  = (const float*)d_in[9];
  const float* W_wk  = (const float*)d_in[10];
  const float* b_wk  = (const float*)d_in[11];
  const float* W_wv  = (const float*)d_in[12];
  const float* b_wv  = (const float*)d_in[13];
  const float* W_er  = (const float*)d_in[14];
  const float* b_er  = (const float*)d_in[15];
  float* out = (float*)d_out;
  (void)in_sizes; (void)n_in; (void)out_size;

  char* ws = (char*)d_ws;
  size_t off = 0;
  auto alloc = [&](size_t bytes) -> void* {
    off = (off + 255) & ~(size_t)255;
    void* p = ws + off;
    off += bytes;
    return p;
  };
  float* EMB      = (float*)alloc((size_t)2048*256*4);
  float* G_emb    = (float*)alloc((size_t)2048*2048*4);
  float* H_all    = (float*)alloc((size_t)2048*512*4);
  float* H_pub    = (float*)alloc((size_t)16*512*4);
  float* mem_g    = (float*)alloc((size_t)16*1024*64*4);
  float* projpub  = (float*)alloc((size_t)2*16*1024*4);
  float* gatespub = (float*)alloc((size_t)16*2048*4);
  u64*   cand     = (u64*)alloc((size_t)16*8*8*8*8);
  u64*   wlist    = (u64*)alloc((size_t)16*32*8);
  float* WT       = (float*)alloc((size_t)64*2048*4);
  uint*  arrv     = (uint*)alloc((size_t)NLINES*32*4);
  ushort* BThi = (ushort*)alloc((size_t)VOCAB*512*2);
  ushort* BTlo = (ushort*)alloc((size_t)VOCAB*512*2);
  const bool use_mfma = (off <= ws_size);

  hipMemsetAsync(arrv, 0, (size_t)NLINES*32*4, stream);
  prep_emb<<<2048, 256, 0, stream>>>(E, seq, EMB);
  gemm_emb<<<1024, 256, 0, stream>>>(EMB, W_ih, b_ih, b_hh, G_emb);
  make_wrvT<<<512, 256, 0, stream>>>(W_ih, WT);
  if (use_mfma)
    split_BT<<<16000, 256, 0, stream>>>(W_out, BThi, BTlo);
  int grid = NWK + NBT + (use_mfma ? NGEMM : 0);
  recur_kernel<<<grid, 256, 0, stream>>>(
      W_hh, WT, W_rk, b_rk, W_wk, b_wk, W_wv, b_wv, W_er, b_er,
      G_emb, H_all, H_pub, mem_g, projpub, gatespub, cand, wlist,
      BThi, BTlo, b_out, out, arrv);
  if (!use_mfma)
    gemm_out<<<16*500, 256, 0, stream>>>(H_all, W_out, b_out, out);
}

// Round 16
// 6384.998 us; speedup vs baseline: 1.0437x; 1.0437x over previous
//
#include <hip/hip_runtime.h>
#include <hip/hip_bf16.h>
#include <stdint.h>

typedef unsigned int uint;
typedef unsigned short ushort;
typedef unsigned long long u64;
typedef __attribute__((ext_vector_type(8))) short s8v;
typedef __attribute__((ext_vector_type(4))) float f4v;

#define T_STEPS 128
#define BQ 16
#define HID 512
#define NSLOT 1024
#define MD 64
#define VOCAB 32000
#define BETA 1.000001f
#define EPSN 1e-8f

#define NWK 128          // worker WGs (proj+slot+gp roles)
#define NBT 16           // batch WGs (merge+rv+gates+LSTM)

// flag lines (128B apart), monotonic generations, memset-0 per launch
#define LF_FH(b)  ((b)*32)            // h(t) ready (gen t+1); batch -> workers
#define LF_FP(w)  ((16+(w))*32)       // proj WG w keys+ew for t (gen t+1)
#define LF_FC(w)  ((48+(w))*32)       // slot WG w cand for t (gen t+1)
#define LF_FW(b)  ((176+(b))*32)      // batch b wlist(t) visible (gen t+1)
#define LF_FG(w)  ((192+(w))*32)      // gp(t) from worker w (gen t+1)
#define NLINES    320

// agent-coherent (bypass L1/L2); batched waitcnt (+sched_barrier, rule #18)
#define AL4(dst, p) asm volatile("global_load_dwordx4 %0, %1, off sc0 sc1" : "=v"(dst) : "v"(p))
#define ALF(dst, p) asm volatile("global_load_dword %0, %1, off sc0 sc1" : "=v"(dst) : "v"(p))
#define AWAIT() do { asm volatile("s_waitcnt vmcnt(0)" ::: "memory"); __builtin_amdgcn_sched_barrier(0); } while(0)
#define DRAIN() asm volatile("s_waitcnt vmcnt(0)" ::: "memory")

__device__ __forceinline__ float sigm(float x){ return 1.f/(1.f+expf(-x)); }
__device__ __forceinline__ void astoref(float* p, float v){
  __hip_atomic_store(p, v, __ATOMIC_RELAXED, __HIP_MEMORY_SCOPE_AGENT);
}
__device__ __forceinline__ void astoreu32(uint* p, uint v){
  __hip_atomic_store(p, v, __ATOMIC_RELAXED, __HIP_MEMORY_SCOPE_AGENT);
}
__device__ __forceinline__ void astoreu64(u64* p, u64 v){
  __hip_atomic_store(p, v, __ATOMIC_RELAXED, __HIP_MEMORY_SCOPE_AGENT);
}
__device__ __forceinline__ u64 aloadu64(const u64* p){
  return __hip_atomic_load((u64*)p, __ATOMIC_RELAXED, __HIP_MEMORY_SCOPE_AGENT);
}
__device__ __forceinline__ uint aloadu32(const uint* p){
  return __hip_atomic_load((uint*)p, __ATOMIC_RELAXED, __HIP_MEMORY_SCOPE_AGENT);
}
__device__ __forceinline__ void poll1(const uint* p, uint gen){
  while (aloadu32(p) < gen) __builtin_amdgcn_s_sleep(2);
}

// pack (score, slot): u64 max == (max value, min slot on ties) — matches lax.top_k
__device__ __forceinline__ u64 packsc(float v, int slot){
  uint u = __float_as_uint(v);
  u = (u & 0x80000000u) ? ~u : (u | 0x80000000u);
  return ((u64)u << 10) | (u64)(1023 - slot);
}
__device__ __forceinline__ float unpackval(u64 p){
  uint u = (uint)(p >> 10);
  uint bits = (u & 0x80000000u) ? (u & 0x7fffffffu) : ~u;
  return __uint_as_float(bits);
}
__device__ __forceinline__ int unpackslot(u64 p){ return 1023 - (int)(p & 1023u); }

// bf16 split helpers
__device__ __forceinline__ ushort f2bf(float x){
  __hip_bfloat16 h = __float2bfloat16(x);
  return *(ushort*)&h;
}
__device__ __forceinline__ float bf2f(ushort u){
  __hip_bfloat16 h; *(ushort*)&h = u;
  return __bfloat162float(h);
}

// LDS float offsets (worker); batch uses low region
#define L_MEM  0
#define L_NRM  8704
#define L_HS   8832
#define L_KEY  17088
#define L_KNRM 17600
#define L_SC   17608
#define L_WV   18632
#define L_ER   18888
#define L_WL   19144
#define L_TOT  19208

// ---------------- pre-kernels ----------------
__global__ __launch_bounds__(256) void prep_emb(const float* __restrict__ E,
                                                const int* __restrict__ seq,
                                                float* __restrict__ EMB){
  int m = blockIdx.x, t = m >> 4, b = m & 15;
  int x = seq[b*T_STEPS + t];
  EMB[(size_t)m*256 + threadIdx.x] = E[(size_t)x*256 + threadIdx.x];
}

// G_emb[m][p] packed p=u*4+g, r=g*512+u
__global__ __launch_bounds__(256) void gemm_emb(const float* __restrict__ A,
                                                const float* __restrict__ W_ih,
                                                const float* __restrict__ b_ih,
                                                const float* __restrict__ b_hh,
                                                float* __restrict__ C){
  __shared__ __align__(16) float As[16*68];
  __shared__ __align__(16) float Bs[16*68];
  int mt = blockIdx.x & 31, nt = blockIdx.x >> 5;
  int m0 = mt*64, n0 = nt*64;
  int tx = threadIdx.x & 15, ty = threadIdx.x >> 4;
  float acc[4][4] = {};
  for (int k0 = 0; k0 < 256; k0 += 16){
    int mm = threadIdx.x >> 2, kq = (threadIdx.x & 3)*4;
    float4 a = *(const float4*)(A + (size_t)(m0+mm)*256 + k0 + kq);
    As[(kq+0)*68+mm]=a.x; As[(kq+1)*68+mm]=a.y; As[(kq+2)*68+mm]=a.z; As[(kq+3)*68+mm]=a.w;
    int pp = n0 + mm;
    int r = (pp & 3)*512 + (pp >> 2);
    float4 bv = *(const float4*)(W_ih + (size_t)r*320 + k0 + kq);
    Bs[(kq+0)*68+mm]=bv.x; Bs[(kq+1)*68+mm]=bv.y; Bs[(kq+2)*68+mm]=bv.z; Bs[(kq+3)*68+mm]=bv.w;
    __syncthreads();
    #pragma unroll
    for (int kk = 0; kk < 16; ++kk){
      float4 av = *(const float4*)(As + kk*68 + ty*4);
      float4 bb = *(const float4*)(Bs + kk*68 + tx*4);
      float aa[4] = {av.x,av.y,av.z,av.w};
      float bv2[4] = {bb.x,bb.y,bb.z,bb.w};
      #pragma unroll
      for (int i = 0; i < 4; ++i)
        #pragma unroll
        for (int j = 0; j < 4; ++j)
          acc[i][j] = fmaf(aa[i], bv2[j], acc[i][j]);
    }
    __syncthreads();
  }
  #pragma unroll
  for (int i = 0; i < 4; ++i){
    int m = m0 + ty*4 + i;
    #pragma unroll
    for (int j = 0; j < 4; ++j){
      int pp = n0 + tx*4 + j;
      int r = (pp & 3)*512 + (pp >> 2);
      C[(size_t)m*2048 + pp] = acc[i][j] + b_ih[r] + b_hh[r];
    }
  }
}

// WT[k][p] = W_ih[r(p)][256+k]  (packed-p rv-weight transpose)
__global__ __launch_bounds__(256) void make_wrvT(const float* __restrict__ W_ih,
                                                 float* __restrict__ WT){
  int idx = blockIdx.x*256 + threadIdx.x;
  int k = idx >> 11, p = idx & 2047;
  int r = (p & 3)*512 + (p >> 2);
  WT[idx] = W_ih[(size_t)r*320 + 256 + k];
}

// ---- split W_out (512x32000 fp32) -> BThi/BTlo [32000][512] bf16 (transposed) ----
__global__ __launch_bounds__(256) void split_BT(const float* __restrict__ W,
                                                ushort* __restrict__ BThi,
                                                ushort* __restrict__ BTlo){
  __shared__ float tl[32][33];
  int kt = blockIdx.x & 15, nt = blockIdx.x >> 4;
  int k0 = kt*32, n0 = nt*32;
  int tx = threadIdx.x & 31, ty = threadIdx.x >> 5;
  #pragma unroll
  for (int i = 0; i < 4; ++i)
    tl[ty + i*8][tx] = W[(size_t)(k0 + ty + i*8)*VOCAB + n0 + tx];
  __syncthreads();
  #pragma unroll
  for (int i = 0; i < 4; ++i){
    float x = tl[tx][ty + i*8];
    ushort hi = f2bf(x);
    ushort lo = f2bf(x - bf2f(hi));
    size_t o = (size_t)(n0 + ty + i*8)*512 + k0 + tx;
    BThi[o] = hi; BTlo[o] = lo;
  }
}

// ---- split H_all (2048x512 fp32) -> Ahi/Alo bf16 ----
__global__ __launch_bounds__(256) void split_A(const float* __restrict__ H,
                                               ushort* __restrict__ Ahi,
                                               ushort* __restrict__ Alo){
  int idx = blockIdx.x*256 + threadIdx.x;
  float x = H[idx];
  ushort hi = f2bf(x);
  Ahi[idx] = hi;
  Alo[idx] = f2bf(x - bf2f(hi));
}

// ---------------- R16 recurrence: R14 verbatim (proven 5.99 ms) ----------------
// workers publish gp(t)=G_emb(t+1)+W_hh·h(t); batch computes gates = gp + WT·rv locally.
__global__ __launch_bounds__(256) void recur_kernel(
    const float* __restrict__ W_hh, const float* __restrict__ WT,
    const float* __restrict__ W_rk, const float* __restrict__ b_rk,
    const float* __restrict__ W_wk, const float* __restrict__ b_wk,
    const float* __restrict__ W_wv, const float* __restrict__ b_wv,
    const float* __restrict__ W_er, const float* __restrict__ b_er,
    const float* __restrict__ G_emb, float* __restrict__ H_all,
    float* __restrict__ H_pub, float* __restrict__ mem_g,
    float* __restrict__ projpub, float* __restrict__ gatespub,
    u64* __restrict__ cand, u64* __restrict__ wlist,
    uint* __restrict__ arrv)
{
  __shared__ __align__(16) float smem[L_TOT];
  const int tid = threadIdx.x;
  const int wg  = blockIdx.x;

  if (wg < NWK){
    // =================== WORKER ===================
    float* mem_s  = smem + L_MEM;
    float* nrm_s  = smem + L_NRM;
    float* hs     = smem + L_HS;
    float* key_s  = smem + L_KEY;
    float* knrm_s = smem + L_KNRM;
    float* sc_s   = smem + L_SC;
    float* wv_s   = smem + L_WV;
    float* er_s   = smem + L_ER;
    u64*   wl_s   = (u64*)(smem + L_WL);

    const int b_s = wg >> 3, rg = wg & 7, s0 = rg*128;
    const int gb = tid >> 4, gc = tid & 15;
    const int pcol = wg*16 + gc;
    const int rrow = (pcol & 3)*512 + (pcol >> 2);
    float* mslice_g = mem_g + ((size_t)b_s*NSLOT + s0)*MD;
    const float* W1 = (wg < 16) ? W_rk : W_wk;
    const float* B1 = (wg < 16) ? b_rk : b_wk;
    const float* W2 = (wg < 16) ? W_wv : W_er;
    const float* B2 = (wg < 16) ? b_wv : b_er;
    const int cc = (wg & 15)*16 + gc;
    const float pb1 = (wg < 32) ? B1[cc] : 0.f;
    const float pb2 = (wg < 32) ? B2[cc] : 0.f;

    for (int i = tid; i < 128*MD; i += 256){
      mem_s[(i >> 6)*68 + (i & 63)] = 1e-6f;
      astoref(mslice_g + i, 1e-6f);
    }
    __syncthreads();
    {
      int s = tid >> 1, half = tid & 1;
      const float4* mp = (const float4*)(mem_s + s*68 + half*32);
      float sum = 0.f;
      #pragma unroll
      for (int q = 0; q < 8; ++q){
        float4 v = mp[q];
        sum = fmaf(v.x,v.x,sum); sum = fmaf(v.y,v.y,sum);
        sum = fmaf(v.z,v.z,sum); sum = fmaf(v.w,v.w,sum);
      }
      sum += __shfl_xor(sum, 1);
      if (half == 0) nrm_s[s] = sqrtf(sum) + EPSN;
    }
    __syncthreads();

    #pragma clang loop unroll(disable)
    for (int t = 0; t < T_STEPS-1; ++t){
      const int par = t & 1, parp = par ^ 1;
      if (t > 0){
        if (tid == 0) poll1(arrv + LF_FW(b_s), (uint)t);
        __syncthreads();
        if (tid < 32) wl_s[tid] = aloadu64(wlist + (size_t)b_s*32 + tid);
        if (tid < 64){
          float4 v; AL4(v, (const float4*)(projpub + (size_t)parp*BQ*1024 + (size_t)b_s*1024 + 512) + tid);
          AWAIT();
          *(float4*)(wv_s + tid*4) = v;
        } else if (tid < 128){
          int i = tid - 64;
          float4 v; AL4(v, (const float4*)(projpub + (size_t)parp*BQ*1024 + (size_t)b_s*1024 + 768) + i);
          AWAIT();
          *(float4*)(er_s + i*4) = v;
        }
        __syncthreads();
        if (tid < 64){
          const int d = tid;
          #pragma unroll 1
          for (int e = 0; e < 32; ++e){
            u64 w64 = wl_s[e];
            int sl = (int)(w64 & 0xffffffffu);
            if (sl >= s0 && sl < s0+128){
              float w = __uint_as_float((uint)(w64 >> 32));
              mem_s[(sl-s0)*68 + d] *= (1.f - w*er_s[(e >> 3)*64 + d]);
            }
          }
          #pragma unroll 1
          for (int e = 0; e < 32; ++e){
            u64 w64 = wl_s[e];
            int sl = (int)(w64 & 0xffffffffu);
            if (sl >= s0 && sl < s0+128){
              float w = __uint_as_float((uint)(w64 >> 32));
              mem_s[(sl-s0)*68 + d] += w*wv_s[(e >> 3)*64 + d];
            }
          }
          #pragma unroll 1
          for (int e = 0; e < 32; ++e){
            u64 w64 = wl_s[e];
            int sl = (int)(w64 & 0xffffffffu);
            if (sl >= s0 && sl < s0+128)
              astoref(mslice_g + (sl-s0)*MD + d, mem_s[(sl-s0)*68 + d]);
          }
        }
        __syncthreads();
        {
          int s = tid >> 1, half = tid & 1;
          const float4* mp = (const float4*)(mem_s + s*68 + half*32);
          float sum = 0.f;
          #pragma unroll
          for (int q = 0; q < 8; ++q){
            float4 v = mp[q];
            sum = fmaf(v.x,v.x,sum); sum = fmaf(v.y,v.y,sum);
            sum = fmaf(v.z,v.z,sum); sum = fmaf(v.w,v.w,sum);
          }
          sum += __shfl_xor(sum, 1);
          if (half == 0) nrm_s[s] = sqrtf(sum) + EPSN;
        }
      }
      if (tid < 16) poll1(arrv + LF_FH(tid), (uint)(t+1));
      __syncthreads();
      {
        float4 v0,v1,v2,v3,v4,v5,v6,v7;
        const float4* hp = (const float4*)H_pub;
        AL4(v0, hp + tid);        AL4(v1, hp + tid + 256);
        AL4(v2, hp + tid + 512);  AL4(v3, hp + tid + 768);
        AL4(v4, hp + tid + 1024); AL4(v5, hp + tid + 1280);
        AL4(v6, hp + tid + 1536); AL4(v7, hp + tid + 1792);
        AWAIT();
        int i;
        i = tid;        *(float4*)(hs + (i>>7)*516 + (i&127)*4) = v0;
        i = tid + 256;  *(float4*)(hs + (i>>7)*516 + (i&127)*4) = v1;
        i = tid + 512;  *(float4*)(hs + (i>>7)*516 + (i&127)*4) = v2;
        i = tid + 768;  *(float4*)(hs + (i>>7)*516 + (i&127)*4) = v3;
        i = tid + 1024; *(float4*)(hs + (i>>7)*516 + (i&127)*4) = v4;
        i = tid + 1280; *(float4*)(hs + (i>>7)*516 + (i&127)*4) = v5;
        i = tid + 1536; *(float4*)(hs + (i>>7)*516 + (i&127)*4) = v6;
        i = tid + 1792; *(float4*)(hs + (i>>7)*516 + (i&127)*4) = v7;
      }
      __syncthreads();
      if (wg < 32){
        float a0=0.f,a1=0.f,b0=0.f,b1=0.f;
        const float* hp = hs + gb*516;
        const float* w1 = W1 + cc;
        const float* w2 = W2 + cc;
        #pragma unroll 4
        for (int k = 0; k < 512; k += 2){
          float h0 = hp[k], h1 = hp[k+1];
          a0 = fmaf(h0, w1[(size_t)k*256], a0);
          b0 = fmaf(h0, w2[(size_t)k*256], b0);
          a1 = fmaf(h1, w1[(size_t)(k+1)*256], a1);
          b1 = fmaf(h1, w2[(size_t)(k+1)*256], b1);
        }
        float v1 = a0 + a1 + pb1;
        float v2 = b0 + b1 + pb2;
        if (wg >= 16) v2 = sigm(v2);
        astoref(projpub + (size_t)par*BQ*1024 + (size_t)gb*1024 + wg*16 + gc, v1);
        astoref(projpub + (size_t)par*BQ*1024 + (size_t)gb*1024 + 512 + wg*16 + gc, v2);
      }
      DRAIN();
      __syncthreads();
      if (wg < 32 && tid == 0) astoreu32(arrv + LF_FP(wg), (uint)(t+1));
      if (tid < 32) poll1(arrv + LF_FP(tid), (uint)(t+1));
      __syncthreads();
      if (tid < 128){
        float4 kv; AL4(kv, (const float4*)(projpub + (size_t)par*BQ*1024 + (size_t)b_s*1024) + tid);
        AWAIT();
        *(float4*)(key_s + tid*4) = kv;
      }
      __syncthreads();
      if (tid < 8){
        const float4* kp = (const float4*)(key_s + tid*MD);
        float sum = 0.f;
        #pragma unroll
        for (int q = 0; q < 16; ++q){
          float4 v = kp[q];
          sum = fmaf(v.x,v.x,sum); sum = fmaf(v.y,v.y,sum);
          sum = fmaf(v.z,v.z,sum); sum = fmaf(v.w,v.w,sum);
        }
        knrm_s[tid] = sqrtf(sum) + EPSN;
      }
      __syncthreads();
      {
        int s = tid >> 1, kh = tid & 1;
        const float4* mp = (const float4*)(mem_s + s*68);
        float rnm = 1.f / nrm_s[s];
        float acc4[4] = {0.f,0.f,0.f,0.f};
        #pragma unroll
        for (int q = 0; q < 16; ++q){
          float4 m = mp[q];
          #pragma unroll
          for (int kk = 0; kk < 4; ++kk){
            float4 k4 = *(const float4*)(key_s + (kh*4+kk)*MD + q*4);
            acc4[kk] = fmaf(m.x,k4.x,acc4[kk]); acc4[kk] = fmaf(m.y,k4.y,acc4[kk]);
            acc4[kk] = fmaf(m.z,k4.z,acc4[kk]); acc4[kk] = fmaf(m.w,k4.w,acc4[kk]);
          }
        }
        #pragma unroll
        for (int kk = 0; kk < 4; ++kk){
          int key = kh*4 + kk;
          sc_s[key*128 + s] = BETA * acc4[kk] * rnm / knrm_s[key];
        }
      }
      __syncthreads();
      {
        int wid = tid >> 6, lane = tid & 63;
        #pragma unroll
        for (int kk = 0; kk < 2; ++kk){
          int key = wid*2 + kk;
          u64 p0 = packsc(sc_s[key*128 + lane],      s0 + lane);
          u64 p1 = packsc(sc_s[key*128 + 64 + lane], s0 + 64 + lane);
          #pragma unroll
          for (int r = 0; r < 8; ++r){
            u64 m = p0 > p1 ? p0 : p1;
            #pragma unroll
            for (int o = 32; o; o >>= 1){ u64 q = __shfl_xor(m, o); if (q > m) m = q; }
            if (p0 == m) p0 = 0; else if (p1 == m) p1 = 0;
            if (lane == 0) astoreu64(cand + (((size_t)b_s*8 + key)*8 + rg)*8 + r, m);
          }
        }
      }
      DRAIN();
      __syncthreads();
      if (tid == 0) astoreu32(arrv + LF_FC(wg), (uint)(t+1));
      {
        float a0 = G_emb[(size_t)((t+1)*BQ + gb)*2048 + pcol];
        float a1 = 0.f, a2 = 0.f, a3 = 0.f;
        const float4* wh = (const float4*)(W_hh + (size_t)rrow*HID);
        const float4* xv = (const float4*)(hs + gb*516);
        #pragma unroll 2
        for (int k = 0; k < 128; k += 4){
          float4 w, x;
          w=wh[k+0]; x=xv[k+0]; a0=fmaf(w.x,x.x,a0); a0=fmaf(w.y,x.y,a0); a0=fmaf(w.z,x.z,a0); a0=fmaf(w.w,x.w,a0);
          w=wh[k+1]; x=xv[k+1]; a1=fmaf(w.x,x.x,a1); a1=fmaf(w.y,x.y,a1); a1=fmaf(w.z,x.z,a1); a1=fmaf(w.w,x.w,a1);
          w=wh[k+2]; x=xv[k+2]; a2=fmaf(w.x,x.x,a2); a2=fmaf(w.y,x.y,a2); a2=fmaf(w.z,x.z,a2); a2=fmaf(w.w,x.w,a2);
          w=wh[k+3]; x=xv[k+3]; a3=fmaf(w.x,x.x,a3); a3=fmaf(w.y,x.y,a3); a3=fmaf(w.z,x.z,a3); a3=fmaf(w.w,x.w,a3);
        }
        astoref(gatespub + (size_t)gb*2048 + pcol, (a0+a1)+(a2+a3));
      }
      DRAIN();
      __syncthreads();
      if (tid == 0) astoreu32(arrv + LF_FG(wg), (uint)(t+1));
    }
  } else {
    // =================== BATCH WG ===================
    const int b = wg - NWK;
    float* rv_st = smem;            // [4][64]
    float* rv_s  = smem + 256;      // [64]
    float* gl    = smem + 320;      // [2048]
    float c0, c1;
    {
      float4 gA = *(const float4*)(G_emb + (size_t)b*2048 + tid*8);
      float4 gB = *(const float4*)(G_emb + (size_t)b*2048 + tid*8 + 4);
      c0 = sigm(gA.x)*tanhf(gA.z);
      float h0v = sigm(gA.w)*tanhf(c0);
      c1 = sigm(gB.x)*tanhf(gB.z);
      float h1v = sigm(gB.w)*tanhf(c1);
      astoref(H_pub + (size_t)b*HID + tid*2,     h0v);
      astoref(H_pub + (size_t)b*HID + tid*2 + 1, h1v);
      H_all[(size_t)b*HID + tid*2]     = h0v;
      H_all[(size_t)b*HID + tid*2 + 1] = h1v;
    }
    DRAIN();
    __syncthreads();
    if (tid == 0) astoreu32(arrv + LF_FH(b), 1u);

    #pragma clang loop unroll(disable)
    for (int t = 0; t < T_STEPS-1; ++t){
      if (tid < 8) poll1(arrv + LF_FC(b*8 + tid), (uint)(t+1));
      __syncthreads();
      {
        int wid = tid >> 6, lane = tid & 63;
        #pragma unroll
        for (int kk = 0; kk < 2; ++kk){
          int key = wid*2 + kk;
          u64 pv = aloadu64(cand + (((size_t)b*8 + key)*8 + (lane >> 3))*8 + (lane & 7));
          u64 sel = 0;
          #pragma unroll
          for (int r = 0; r < 8; ++r){
            u64 m = pv;
            #pragma unroll
            for (int o = 32; o; o >>= 1){ u64 q = __shfl_xor(m, o); if (q > m) m = q; }
            if (pv == m) pv = 0;
            if (lane == r) sel = m;
          }
          float val = unpackval(sel);
          int slot = unpackslot(sel);
          float vmax = __shfl(val, 0);
          float e = (lane < 8) ? expf(val - vmax) : 0.f;
          float ssum = e;
          #pragma unroll
          for (int o = 32; o; o >>= 1) ssum += __shfl_xor(ssum, o);
          float w = e / ssum;
          if (key < 4){
            int sls[8];
            #pragma unroll
            for (int i = 0; i < 8; ++i) sls[i] = __shfl(slot, i);
            float mv[8];
            #pragma unroll
            for (int i = 0; i < 8; ++i)
              ALF(mv[i], mem_g + ((size_t)b*NSLOT + sls[i])*MD + lane);
            AWAIT();
            float acc = 0.f;
            #pragma unroll
            for (int i = 0; i < 8; ++i) acc = fmaf(__shfl(w, i), mv[i], acc);
            rv_st[key*64 + lane] = acc;
          } else if (lane < 8){
            astoreu64(wlist + (size_t)b*32 + (key-4)*8 + lane,
                      ((u64)__float_as_uint(w) << 32) | (u64)(uint)slot);
          }
        }
      }
      DRAIN();                    // wlist visible before FW
      __syncthreads();
      if (tid < 64)
        rv_s[tid] = 0.25f*(rv_st[tid] + rv_st[64+tid] + rv_st[128+tid] + rv_st[192+tid]);
      if (tid == 0) astoreu32(arrv + LF_FW(b), (uint)(t+1));
      if (tid < 128) poll1(arrv + LF_FG(tid), (uint)(t+1));
      __syncthreads();
      {
        float g8[8];
        #pragma unroll
        for (int q = 0; q < 8; ++q)
          ALF(g8[q], gatespub + (size_t)b*2048 + tid + 256*q);
        AWAIT();
        #pragma unroll 2
        for (int d = 0; d < 64; ++d){
          float r = rv_s[d];
          const float* wrow = WT + (size_t)d*2048 + tid;
          #pragma unroll
          for (int q = 0; q < 8; ++q)
            g8[q] = fmaf(r, wrow[256*q], g8[q]);
        }
        #pragma unroll
        for (int q = 0; q < 8; ++q) gl[tid + 256*q] = g8[q];
      }
      __syncthreads();
      {
        float gi0 = gl[tid*8+0], gf0 = gl[tid*8+1], gg0 = gl[tid*8+2], go0 = gl[tid*8+3];
        float gi1 = gl[tid*8+4], gf1 = gl[tid*8+5], gg1 = gl[tid*8+6], go1 = gl[tid*8+7];
        c0 = sigm(gf0)*c0 + sigm(gi0)*tanhf(gg0);
        float h0v = sigm(go0)*tanhf(c0);
        c1 = sigm(gf1)*c1 + sigm(gi1)*tanhf(gg1);
        float h1v = sigm(go1)*tanhf(c1);
        astoref(H_pub + (size_t)b*HID + tid*2,     h0v);
        astoref(H_pub + (size_t)b*HID + tid*2 + 1, h1v);
        H_all[(size_t)((t+1)*BQ + b)*HID + tid*2]     = h0v;
        H_all[(size_t)((t+1)*BQ + b)*HID + tid*2 + 1] = h1v;
      }
      DRAIN();
      __syncthreads();
      if (tid == 0) astoreu32(arrv + LF_FH(b), (uint)(t+2));
    }
  }
}

// ---------------- MFMA bf16x4-split logits GEMM (R13-proven) ----------------
#define GM_NT 250
__global__ __launch_bounds__(256) void gemm_mfma(
    const ushort* __restrict__ Ahi, const ushort* __restrict__ Alo,
    const ushort* __restrict__ BThi, const ushort* __restrict__ BTlo,
    const float* __restrict__ bias, float* __restrict__ C)
{
  __shared__ __align__(16) ushort ldsu[4*128*40];
  const int tid = threadIdx.x;
  int mt = blockIdx.x / GM_NT, nt = blockIdx.x - mt*GM_NT;
  int m0 = mt*128, n0 = nt*128;
  const int wv = tid >> 6, lane = tid & 63;
  const int wm = (wv & 1)*64, wn = (wv >> 1)*64;
  const int fr = lane & 15, kh = (lane >> 4)*8;

  f4v acc[4][4];
  #pragma unroll
  for (int i = 0; i < 4; ++i)
    #pragma unroll
    for (int j = 0; j < 4; ++j)
      acc[i][j] = (f4v){0.f,0.f,0.f,0.f};

  const int sr = tid & 127, sel = tid >> 7;
  const ushort* srcA = (sel ? Alo : Ahi) + (size_t)(m0 + sr)*512;
  const ushort* srcB = (sel ? BTlo : BThi) + (size_t)(n0 + sr)*512;
  ushort* dstA = ldsu + (size_t)sel*5120 + sr*40;
  ushort* dstB = ldsu + (size_t)(2+sel)*5120 + sr*40;

  for (int ks = 0; ks < 16; ++ks){
    const int k0 = ks*32;
    __syncthreads();
    {
      uint4 a0 = *(const uint4*)(srcA + k0);
      uint4 a1 = *(const uint4*)(srcA + k0 + 8);
      uint4 a2 = *(const uint4*)(srcA + k0 + 16);
      uint4 a3 = *(const uint4*)(srcA + k0 + 24);
      uint4 b0 = *(const uint4*)(srcB + k0);
      uint4 b1 = *(const uint4*)(srcB + k0 + 8);
      uint4 b2 = *(const uint4*)(srcB + k0 + 16);
      uint4 b3 = *(const uint4*)(srcB + k0 + 24);
      *(uint4*)(dstA +  0) = a0; *(uint4*)(dstA +  8) = a1;
      *(uint4*)(dstA + 16) = a2; *(uint4*)(dstA + 24) = a3;
      *(uint4*)(dstB +  0) = b0; *(uint4*)(dstB +  8) = b1;
      *(uint4*)(dstB + 16) = b2; *(uint4*)(dstB + 24) = b3;
    }
    __syncthreads();
    s8v ah[4], al[4], bh[4], bl[4];
    #pragma unroll
    for (int mi = 0; mi < 4; ++mi){
      ah[mi] = *(const s8v*)(ldsu + 0*5120 + (wm + mi*16 + fr)*40 + kh);
      al[mi] = *(const s8v*)(ldsu + 1*5120 + (wm + mi*16 + fr)*40 + kh);
    }
    #pragma unroll
    for (int ni = 0; ni < 4; ++ni){
      bh[ni] = *(const s8v*)(ldsu + 2*5120 + (wn + ni*16 + fr)*40 + kh);
      bl[ni] = *(const s8v*)(ldsu + 3*5120 + (wn + ni*16 + fr)*40 + kh);
    }
    #pragma unroll
    for (int mi = 0; mi < 4; ++mi)
      #pragma unroll
      for (int ni = 0; ni < 4; ++ni){
        acc[mi][ni] = __builtin_amdgcn_mfma_f32_16x16x32_bf16(ah[mi], bh[ni], acc[mi][ni], 0, 0, 0);
        acc[mi][ni] = __builtin_amdgcn_mfma_f32_16x16x32_bf16(ah[mi], bl[ni], acc[mi][ni], 0, 0, 0);
        acc[mi][ni] = __builtin_amdgcn_mfma_f32_16x16x32_bf16(al[mi], bh[ni], acc[mi][ni], 0, 0, 0);
        acc[mi][ni] = __builtin_amdgcn_mfma_f32_16x16x32_bf16(al[mi], bl[ni], acc[mi][ni], 0, 0, 0);
      }
  }
  #pragma unroll
  for (int ni = 0; ni < 4; ++ni){
    int col = n0 + wn + ni*16 + fr;
    float bz = bias[col];
    #pragma unroll
    for (int mi = 0; mi < 4; ++mi){
      #pragma unroll
      for (int j = 0; j < 4; ++j){
        int row = m0 + wm + mi*16 + (lane >> 4)*4 + j;
        C[((size_t)(row & 15)*T_STEPS + (row >> 4))*VOCAB + col] = acc[mi][ni][j] + bz;
      }
    }
  }
}

// ---------------- fp32 fallback GEMM ----------------
__global__ __launch_bounds__(256) void gemm_out(const float* __restrict__ A,
                                                const float* __restrict__ Bmat,
                                                const float* __restrict__ bias,
                                                float* __restrict__ C){
  __shared__ __align__(16) float As[16*132];
  __shared__ __align__(16) float Bs[16*64];
  int mt = blockIdx.x & 15, nt = blockIdx.x >> 4;
  int m0 = mt*128, n0 = nt*64;
  int tx = threadIdx.x & 15, ty = threadIdx.x >> 4;
  float acc[8][4] = {};
  for (int k0 = 0; k0 < 512; k0 += 16){
    int mm = threadIdx.x >> 1, kq = (threadIdx.x & 1)*8;
    float4 a0 = *(const float4*)(A + (size_t)(m0+mm)*512 + k0 + kq);
    float4 a1 = *(const float4*)(A + (size_t)(m0+mm)*512 + k0 + kq + 4);
    As[(kq+0)*132+mm]=a0.x; As[(kq+1)*132+mm]=a0.y; As[(kq+2)*132+mm]=a0.z; As[(kq+3)*132+mm]=a0.w;
    As[(kq+4)*132+mm]=a1.x; As[(kq+5)*132+mm]=a1.y; As[(kq+6)*132+mm]=a1.z; As[(kq+7)*132+mm]=a1.w;
    int kk2 = threadIdx.x >> 4, nq = (threadIdx.x & 15)*4;
    *(float4*)(Bs + kk2*64 + nq) = *(const float4*)(Bmat + (size_t)(k0+kk2)*VOCAB + n0 + nq);
    __syncthreads();
    #pragma unroll
    for (int kk = 0; kk < 16; ++kk){
      float4 x0 = *(const float4*)(As + kk*132 + ty*8);
      float4 x1 = *(const float4*)(As + kk*132 + ty*8 + 4);
      float4 bv = *(const float4*)(Bs + kk*64 + tx*4);
      float aa[8] = {x0.x,x0.y,x0.z,x0.w,x1.x,x1.y,x1.z,x1.w};
      float bb[4] = {bv.x,bv.y,bv.z,bv.w};
      #pragma unroll
      for (int i = 0; i < 8; ++i)
        #pragma unroll
        for (int j = 0; j < 4; ++j)
          acc[i][j] = fmaf(aa[i], bb[j], acc[i][j]);
    }
    __syncthreads();
  }
  #pragma unroll
  for (int i = 0; i < 8; ++i){
    int m = m0 + ty*8 + i;
    int bq = m & 15, tt = m >> 4;
    float* crow = C + ((size_t)bq*T_STEPS + tt)*VOCAB + n0 + tx*4;
    #pragma unroll
    for (int j = 0; j < 4; ++j) crow[j] = acc[i][j] + bias[n0 + tx*4 + j];
  }
}

extern "C" void kernel_launch(void* const* d_in, const int* in_sizes, int n_in,
                              void* d_out, int out_size, void* d_ws, size_t ws_size,
                              hipStream_t stream){
  const int*   seq   = (const int*)d_in[0];
  const float* E     = (const float*)d_in[1];
  const float* W_ih  = (const float*)d_in[2];
  const float* W_hh  = (const float*)d_in[3];
  const float* b_ih  = (const float*)d_in[4];
  const float* b_hh  = (const float*)d_in[5];
  const float* W_out = (const float*)d_in[6];
  const float* b_out = (const float*)d_in[7];
  const float* W_rk  = (const float*)d_in[8];
  const float* b_rk  = (const float*)d_in[9];
  const float* W_wk  = (const float*)d_in[10];
  const float* b_wk  = (const float*)d_in[11];
  const float* W_wv  = (const float*)d_in[12];
  const float* b_wv  = (const float*)d_in[13];
  const float* W_er  = (const float*)d_in[14];
  const float* b_er  = (const float*)d_in[15];
  float* out = (float*)d_out;
  (void)in_sizes; (void)n_in; (void)out_size;

  char* ws = (char*)d_ws;
  size_t off = 0;
  auto alloc = [&](size_t bytes) -> void* {
    off = (off + 255) & ~(size_t)255;
    void* p = ws + off;
    off += bytes;
    return p;
  };
  float* EMB      = (float*)alloc((size_t)2048*256*4);
  float* G_emb    = (float*)alloc((size_t)2048*2048*4);
  float* H_all    = (float*)alloc((size_t)2048*512*4);
  float* H_pub    = (float*)alloc((size_t)16*512*4);
  float* mem_g    = (float*)alloc((size_t)16*1024*64*4);
  float* projpub  = (float*)alloc((size_t)2*16*1024*4);
  float* gatespub = (float*)alloc((size_t)16*2048*4);
  u64*   cand     = (u64*)alloc((size_t)16*8*8*8*8);
  u64*   wlist    = (u64*)alloc((size_t)16*32*8);
  float* WT       = (float*)alloc((size_t)64*2048*4);
  uint*  arrv     = (uint*)alloc((size_t)NLINES*32*4);
  ushort* Ahi  = (ushort*)alloc((size_t)2048*512*2);
  ushort* Alo  = (ushort*)alloc((size_t)2048*512*2);
  ushort* BThi = (ushort*)alloc((size_t)VOCAB*512*2);
  ushort* BTlo = (ushort*)alloc((size_t)VOCAB*512*2);
  const bool use_mfma = (off <= ws_size);

  hipMemsetAsync(arrv, 0, (size_t)NLINES*32*4, stream);
  prep_emb<<<2048, 256, 0, stream>>>(E, seq, EMB);
  gemm_emb<<<1024, 256, 0, stream>>>(EMB, W_ih, b_ih, b_hh, G_emb);
  make_wrvT<<<512, 256, 0, stream>>>(W_ih, WT);
  if (use_mfma)
    split_BT<<<16000, 256, 0, stream>>>(W_out, BThi, BTlo);
  recur_kernel<<<NWK + NBT, 256, 0, stream>>>(
      W_hh, WT, W_rk, b_rk, W_wk, b_wk, W_wv, b_wv, W_er, b_er,
      G_emb, H_all, H_pub, mem_g, projpub, gatespub, cand, wlist, arrv);
  if (use_mfma){
    split_A<<<4096, 256, 0, stream>>>(H_all, Ahi, Alo);
    gemm_mfma<<<16*GM_NT, 256, 0, stream>>>(Ahi, Alo, BThi, BTlo, b_out, out);
  } else {
    gemm_out<<<16*500, 256, 0, stream>>>(H_all, W_out, b_out, out);
  }
}